// Round 4
// baseline (271.360 us; speedup 1.0000x reference)
//
#include <hip/hip_runtime.h>

typedef short bf16x8 __attribute__((ext_vector_type(8)));
typedef short short8 __attribute__((ext_vector_type(8)));
typedef float f32x16 __attribute__((ext_vector_type(16)));

#define DD 512
#define NG 512

typedef __attribute__((address_space(3))) void lds_void;
typedef __attribute__((address_space(1))) void glb_void;

static __device__ __forceinline__ void gload_lds16(const void* g, void* l) {
  __builtin_amdgcn_global_load_lds((const glb_void*)g, (lds_void*)l, 16, 0, 0);
}

// counted waitcnt: keeps staging loads in flight across barriers (T4)
#define WAITV(n) asm volatile("s_waitcnt vmcnt(" #n ") lgkmcnt(0)" ::: "memory")

// split f32 into bf16 hi (truncate) + bf16 lo (round) ; f ≈ hi + lo, ~2^-16 rel err
static __device__ __forceinline__ void cvt_hl(float f, unsigned short& h, unsigned short& l) {
  unsigned u = __builtin_bit_cast(unsigned, f);
  unsigned hu = u & 0xffff0000u;
  float fh = __builtin_bit_cast(float, hu);
  float fl = f - fh;                       // exact in f32
  unsigned ul = __builtin_bit_cast(unsigned, fl);
  h = (unsigned short)(hu >> 16);
  l = (unsigned short)((ul + 0x8000u) >> 16);
}

// fast tanh: 1 - 2/(e^{2v}+1), native exp/rcp (~1e-6 abs err, saturates correctly)
static __device__ __forceinline__ float fast_tanh(float v) {
  float e = __expf(2.0f * v);
  return 1.0f - 2.0f * __builtin_amdgcn_rcpf(e + 1.0f);
}

// Whl layout: [ny(2)][kt(32)][ct(8)][hl(2)][lane(64)=khalf*32+c31][e(8 bf16)]
// One (ny,kt) slice = 16 KB, contiguous -> staged linearly by global_load_lds.
// B-fragment ds_read for 32x32x16 is then exactly lds + lane*16 (+ct*2048
// +hl*1024): 64 lanes read 1024 contiguous bytes -> zero bank conflicts.
__global__ __launch_bounds__(256) void k_convert_w(const float* __restrict__ W,
                                                   unsigned char* __restrict__ Whl) {
  int t = blockIdx.x * 256 + threadIdx.x;   // 32768 = 512 W-rows x 64 kgroups(8)
  int r512 = t >> 6, kg = t & 63;
  int ny = r512 >> 8, col = r512 & 255;
  int ct = col >> 5, c31 = col & 31;
  int kt = kg >> 1, khalf = kg & 1;
  const float* p = W + (size_t)r512 * DD + kg * 8;
  short8 h, l;
#pragma unroll
  for (int j = 0; j < 8; ++j) {
    unsigned short hh, ll;
    cvt_hl(p[j], hh, ll);
    h[j] = (short)hh;
    l[j] = (short)ll;
  }
  unsigned char* dst = Whl + (size_t)ny * 524288 + (size_t)kt * 16384 +
                       ct * 2048 + (khalf * 32 + c31) * 16;
  *(short8*)dst = h;             // hi plane
  *(short8*)(dst + 1024) = l;    // lo plane
}

// Fused GEMM(tanh-gate) + query-dot.  Wave = 32 rows x 256 cols (8 x 32x32x16
// tiles, 3 MFMAs each for f32-accurate hi/lo bf16).  Block = 4 waves = 128
// rows; blockIdx.x = col-half (ny), blockIdx.y = row-block (adjacent blocks
// share x rows -> L2/L3 hit on the 2nd col-half pass).
// B staged via ring-4 LDS (16KB slices) with counted vmcnt - never drained.
__global__ __launch_bounds__(256, 2) void k_gemm_score(
    const float* __restrict__ x, const unsigned char* __restrict__ Whl,
    const float* __restrict__ bias, const float* __restrict__ query,
    float* __restrict__ score_part, int N) {
  __shared__ unsigned char lds[4][16384];
  const int tid = threadIdx.x;
  const int wave = tid >> 6;
  const int lane = tid & 63;
  const int l31 = lane & 31;
  const int kh = lane >> 5;          // k-half within fragment
  const int ny = blockIdx.x;
  const int row0 = blockIdx.y * 128 + wave * 32;

  const float* xp = x + (size_t)(row0 + l31) * DD + kh * 8;
  const unsigned char* wsrc = Whl + (size_t)ny * 524288 +
                              (size_t)wave * 4096 + (size_t)lane * 16;

  f32x16 acc[8];
#pragma unroll
  for (int ct = 0; ct < 8; ++ct)
#pragma unroll
    for (int r = 0; r < 16; ++r) acc[ct][r] = 0.f;

  // prologue: stage slices 0..2 (12 gloads/wave in flight)
#pragma unroll
  for (int s = 0; s < 3; ++s)
#pragma unroll
    for (int i = 0; i < 4; ++i)
      gload_lds16(wsrc + s * 16384 + i * 1024, &lds[s][wave * 4096 + i * 1024]);

  for (int kt = 0; kt < 32; ++kt) {
    // slice-kt readiness: its 4 gloads are 3 issue-regions old; newer regions
    // hold <= 12 ops (2x [4 stage gloads + 2 A-loads]).  Tail shrinks.
    if (kt == 0)       WAITV(8);
    else if (kt == 1)  WAITV(10);
    else if (kt <= 29) WAITV(12);
    else if (kt == 30) WAITV(8);
    else               WAITV(4);
    __builtin_amdgcn_s_barrier();
    asm volatile("" ::: "memory");   // pin following mem ops below the barrier

    if (kt < 29) {  // stage slice kt+3 into ring slot; readers finished at kt-1
      const unsigned char* src = wsrc + (size_t)(kt + 3) * 16384;
      unsigned char* dst = &lds[(kt + 3) & 3][wave * 4096];
#pragma unroll
      for (int i = 0; i < 4; ++i)
        gload_lds16(src + i * 1024, dst + i * 1024);
    }

    // A fragment: 8 consecutive f32 of this lane's row at k = kt*16 + kh*8
    const float4 a0 = *(const float4*)(xp + kt * 16);
    const float4 a1 = *(const float4*)(xp + kt * 16 + 4);
    float af[8] = {a0.x, a0.y, a0.z, a0.w, a1.x, a1.y, a1.z, a1.w};
    bf16x8 ah, al;
#pragma unroll
    for (int j = 0; j < 8; ++j) {
      unsigned short hh, ll;
      cvt_hl(af[j], hh, ll);
      ah[j] = (short)hh;
      al[j] = (short)ll;
    }

    const unsigned char* bb = &lds[kt & 3][lane * 16];
#pragma unroll
    for (int ct = 0; ct < 8; ++ct) {
      bf16x8 bh = *(const bf16x8*)(bb + ct * 2048);
      bf16x8 bl = *(const bf16x8*)(bb + ct * 2048 + 1024);
      acc[ct] = __builtin_amdgcn_mfma_f32_32x32x16_bf16(ah, bh, acc[ct], 0, 0, 0);
      acc[ct] = __builtin_amdgcn_mfma_f32_32x32x16_bf16(al, bh, acc[ct], 0, 0, 0);
      acc[ct] = __builtin_amdgcn_mfma_f32_32x32x16_bf16(ah, bl, acc[ct], 0, 0, 0);
    }
  }

  // epilogue: tanh + query-dot; reduce over 32 cols (lanes) per C row
  float sp[16];
#pragma unroll
  for (int r = 0; r < 16; ++r) sp[r] = 0.f;
#pragma unroll
  for (int ct = 0; ct < 8; ++ct) {
    const int col = ny * 256 + ct * 32 + l31;
    const float bb2 = bias[col];
    const float qq = query[col];
#pragma unroll
    for (int r = 0; r < 16; ++r)
      sp[r] += fast_tanh(acc[ct][r] + bb2) * qq;
  }
#pragma unroll
  for (int r = 0; r < 16; ++r) {
    float v = sp[r];
    v += __shfl_xor(v, 1);
    v += __shfl_xor(v, 2);
    v += __shfl_xor(v, 4);
    v += __shfl_xor(v, 8);
    v += __shfl_xor(v, 16);
    if (l31 == 0)  // C row = (r&3) + 8*(r>>2) + 4*kh  (m74/m101 layout)
      score_part[(size_t)ny * N + row0 + (r & 3) + 8 * (r >> 2) + 4 * kh] = v;
  }
}

// Per-graph: segmented softmax over (sp0+sp1) + weighted sum of x rows -> out[g][512]
__global__ __launch_bounds__(256) void k_softmax_out(
    const float* __restrict__ x, const void* __restrict__ segp,
    const float* __restrict__ sp0, const float* __restrict__ sp1,
    float* __restrict__ out, int N) {
  const int g = blockIdx.x;
  const int tid = threadIdx.x;

  // dtype probe: int64 element N/2-1 is a graph id (<NG) iff buffer is int64.
  const long long probe = ((const long long*)segp)[N / 2 - 1];
  const bool is64 = ((unsigned long long)probe < (unsigned long long)NG);
  const long long* s64 = (const long long*)segp;
  const int* s32 = (const int*)segp;

  int s0, s1;
  {
    int lo = 0, hi = N;
    while (lo < hi) {
      int m = (lo + hi) >> 1;
      long long v = is64 ? s64[m] : (long long)s32[m];
      if (v < (long long)g) lo = m + 1; else hi = m;
    }
    s0 = lo;
    lo = s0; hi = N;
    while (lo < hi) {
      int m = (lo + hi) >> 1;
      long long v = is64 ? s64[m] : (long long)s32[m];
      if (v < (long long)(g + 1)) lo = m + 1; else hi = m;
    }
    s1 = lo;
  }

  __shared__ float red[4];
  __shared__ float wbuf[512];

  float lm = -INFINITY;
  for (int i = s0 + tid; i < s1; i += 256) lm = fmaxf(lm, sp0[i] + sp1[i]);
#pragma unroll
  for (int m = 1; m < 64; m <<= 1) lm = fmaxf(lm, __shfl_xor(lm, m));
  if ((tid & 63) == 0) red[tid >> 6] = lm;
  __syncthreads();
  const float mx = fmaxf(fmaxf(red[0], red[1]), fmaxf(red[2], red[3]));
  __syncthreads();

  float ls = 0.f;
  for (int i = s0 + tid; i < s1; i += 256) ls += expf(sp0[i] + sp1[i] - mx);
#pragma unroll
  for (int m = 1; m < 64; m <<= 1) ls += __shfl_xor(ls, m);
  if ((tid & 63) == 0) red[tid >> 6] = ls;
  __syncthreads();
  const float sum = red[0] + red[1] + red[2] + red[3];
  const float inv = sum > 0.f ? 1.0f / sum : 0.f;

  float a0 = 0.f, a1 = 0.f;
  const int c = tid * 2;
  for (int base = s0; base < s1; base += 512) {
    const int cnt = min(512, s1 - base);
    __syncthreads();
    for (int i = tid; i < cnt; i += 256)
      wbuf[i] = expf(sp0[base + i] + sp1[base + i] - mx) * inv;
    __syncthreads();
#pragma unroll 4
    for (int j = 0; j < cnt; ++j) {
      const float w = wbuf[j];
      const float2 xv = *(const float2*)(x + (size_t)(base + j) * DD + c);
      a0 = fmaf(w, xv.x, a0);
      a1 = fmaf(w, xv.y, a1);
    }
  }
  float* op = out + (size_t)g * DD + c;
  op[0] = a0;
  op[1] = a1;
}

extern "C" void kernel_launch(void* const* d_in, const int* in_sizes, int n_in,
                              void* d_out, int out_size, void* d_ws, size_t ws_size,
                              hipStream_t stream) {
  const float* x = (const float*)d_in[0];
  const void* seg = d_in[1];
  const float* W = (const float*)d_in[2];
  const float* b = (const float*)d_in[3];
  const float* q = (const float*)d_in[4];
  float* out = (float*)d_out;
  const int N = in_sizes[0] / DD;  // 131072

  unsigned char* Whl = (unsigned char*)d_ws;                 // 1 MB packed W (hi/lo)
  float* sp0 = (float*)(Whl + 1048576);                      // N partial scores (ny=0)
  float* sp1 = sp0 + N;                                      // N partial scores (ny=1)

  k_convert_w<<<128, 256, 0, stream>>>(W, Whl);
  dim3 grid(2, N / 128);                                     // x = ny (fastest) -> x-row L3 reuse
  k_gemm_score<<<grid, 256, 0, stream>>>(x, Whl, b, q, sp0, N);
  k_softmax_out<<<NG, 256, 0, stream>>>(x, seg, sp0, sp1, out, N);
}